// Round 3
// baseline (1171.159 us; speedup 1.0000x reference)
//
#include <hip/hip_runtime.h>
#include <hip/hip_fp16.h>
#include <cstddef>
#include <cstdint>

namespace {

constexpr int   kN = 512;
constexpr int   kB = 64;
constexpr float kAlpha = 0.8f;
constexpr float kBig  = 1e8f;
constexpr float kKexp = 144.26950408889634f;    // (1/gamma) * log2(e)
constexpr float kGLn2 = 0.006931471805599453f;  // gamma * ln(2)
constexpr float kWexp = 0.07213475204444817f;   // G * log2(e)

__global__ __launch_bounds__(512)
void dilate_tiled(const float* __restrict__ input,
                  const float* __restrict__ target,
                  uint32_t* __restrict__ Wg,       // per-block 64*4096 u32 (f16x2 weights)
                  float* __restrict__ partials,    // [kB]
                  int b0) {
    __shared__ float sx[512], st_[512], sw_[512];
    __shared__ float bH_R[512], bV_R[512];                 // forward boundaries
    __shared__ float bH_B[512], bH_A[512], bV_C[512], bV_A[512];  // backward contribs
    __shared__ float ccF[64], ccA[64];
    __shared__ float sred[8];
    __shared__ float s_rnn;

    const int tid = threadIdx.x;
    const int r = tid >> 6;       // wave = tile-row
    const int u = tid & 63;       // lane = row within tile
    const int b = b0 + blockIdx.x;
    uint32_t* __restrict__ Wslot = Wg + (size_t)blockIdx.x * (size_t)(64 * 4096);

    sx[tid]  = input[(size_t)b * kN + tid];
    st_[tid] = target[(size_t)b * kN + tid];
    bH_R[tid] = kBig;
    bV_R[tid] = kBig;

    // normalized exponential time weights
    float ew = exp2f(kWexp * (float)tid);
    float wsum = ew;
    #pragma unroll
    for (int off = 32; off; off >>= 1) wsum += __shfl_xor(wsum, off);
    if (u == 0) sred[r] = wsum;
    __syncthreads();
    float tot = 0.f;
    #pragma unroll
    for (int q = 0; q < 8; ++q) tot += sred[q];
    sw_[tid] = ew * (512.0f / tot);
    __syncthreads();

    const float tcur = st_[(r << 6) + u];
    const float wcur = sw_[(r << 6) + u];

    // ---------------- forward soft-DTW (stores f16x2 softmin weights) -------
    for (int d = 0; d < 15; ++d) {
        if (d >= r && d <= r + 7) {
            const int c = d - r;
            uint32_t* __restrict__ wrow = Wslot + (((r << 3) + c) << 12) + (u << 6);
            float vC = bV_R[(r << 6) | u];    // R(i, 64c) from left tile
            float vA = __shfl_up(vC, 1);      // R(i-1, 64c)
            float corner;
            if (r == 0)      corner = (c == 0) ? 0.0f : kBig;
            else if (c == 0) corner = kBig;
            else             corner = ccF[((r - 1) << 3) + (c - 1)];
            if (u == 0) vA = corner;
            float prev = kBig, Bprev = kBig;
            uint32_t q0 = 0, q1 = 0, q2 = 0, q3 = 0;
            const int xbase = (c << 6) - u;
            for (int s = 0; s < 127; ++s) {
                const int v = s - u;
                float B = __shfl_up(prev, 1);              // R(i-1, j)
                const int smin = (s > 63) ? 63 : s;
                const float hbB = bH_R[(c << 6) | smin];
                if (u == 0) B = hbB;
                float A = Bprev;                           // R(i-1, j-1) = last B
                float C = prev;                            // R(i, j-1)
                if (v == 0) { A = vA; C = vC; }
                int xi = xbase + s;
                xi = xi < 0 ? 0 : (xi > 511 ? 511 : xi);
                const float dx = tcur - sx[xi];
                const float dc = wcur * dx * dx;
                const float m = fminf(A, fminf(B, C));
                const float eA = exp2f((m - A) * kKexp);
                const float eB = exp2f((m - B) * kKexp);
                const float eC = exp2f((m - C) * kKexp);
                const float ssum = eA + eB + eC;
                float cur = dc + m - kGLn2 * log2f(ssum);
                const bool valid = (v >= 0) && (v <= 63);
                cur = valid ? cur : kBig;
                // pack transition weights (wb, wc); wa = 1 - wb - wc
                const float rinv = __builtin_amdgcn_rcpf(ssum);
                __half2 hp = __floats2half2_rn(eB * rinv, eC * rinv);
                uint32_t pk = *reinterpret_cast<uint32_t*>(&hp);
                q0 = q1; q1 = q2; q2 = q3; q3 = pk;        // shift register
                if (valid && (v & 3) == 3) {
                    uint4 st4; st4.x = q0; st4.y = q1; st4.z = q2; st4.w = q3;
                    *reinterpret_cast<uint4*>(wrow + (v - 3)) = st4;
                }
                if (s >= 63) {
                    if (u == 63) bH_R[(c << 6) | v] = cur;
                    if (v == 63) bV_R[(r << 6) | u] = cur;
                    if (s == 126 && u == 63) {
                        ccF[(r << 3) + c] = cur;
                        if (r == 7 && c == 7) s_rnn = cur;
                    }
                }
                Bprev = B; prev = cur;
            }
        }
        __syncthreads();
    }

    // ---------------- backward adjoint via stored weights -------------------
    float acc = 0.0f;
    for (int D = 14; D >= 0; --D) {
        if (D >= r && D <= r + 7) {
            const int c = D - r;
            const uint32_t* __restrict__ wrow =
                Wslot + (((r << 3) + c) << 12) + (u << 6);
            float vCin = bV_C[(r << 6) | u];   // cC(u, 64) from right tile
            float vAin = bV_A[(r << 6) | u];   // cA(u, 64) from right tile
            float vAsm = __shfl_down(vAin, 1); // cA(u+1, 64)
            if (u == 63) vAsm = 0.0f;
            if (c == 7) { vCin = 0.0f; vAsm = 0.0f; }
            float ccA_in = 0.0f;
            if (r < 7 && c < 7) ccA_in = ccA[((r + 1) << 3) + (c + 1)];
            float cA2 = 0.f, cAp = 0.f, cBp = 0.f, cCp = 0.f;
            float bhA_prev = 0.0f;
            uint4 pend = *reinterpret_cast<const uint4*>(wrow + 60);  // quad 15
            uint32_t pw = 0, w2 = 0, w1 = 0, w0 = 0;
            int nq = 56;
            const float dij0 = (float)(((r - c) << 6) + 2 * u);
            for (int s = 126; s >= 0; --s) {
                const int v = s - u;
                const bool valid = (v >= 0) && (v <= 63);
                float g = cA2 + cBp;                 // cA(u,v+2)+cB(u,v+1) local
                float gs = __shfl_down(g, 1);        // from lane u+1
                int vbc = s - 63; vbc = vbc < 0 ? 0 : vbc;
                const float bhB = bH_B[(c << 6) | vbc];
                const float bhA = bH_A[(c << 6) | vbc];
                if (u == 63) {
                    const float below = (r < 7) ? bhB : 0.0f;
                    const float bdiag = (v == 63) ? ccA_in
                                                  : ((r < 7) ? bhA_prev : 0.0f);
                    gs = below + bdiag;
                }
                float cCs = cCp, add2 = 0.0f;
                if (v == 63) { cCs = vCin; add2 = vAsm; }
                float E = gs + cCs + add2;
                if (r == 7 && c == 7 && s == 126) E = 1.0f;   // seed E[N,N]
                E = valid ? E : 0.0f;
                const float dij = dij0 - (float)s;
                acc = fmaf(E, dij * dij, acc);
                // weight pipeline (consume v descending; refill per quad)
                if (valid && (v & 3) == 3) {
                    pw = pend.w; w2 = pend.z; w1 = pend.y; w0 = pend.x;
                    pend = *reinterpret_cast<const uint4*>(
                        wrow + (nq < 0 ? 0 : nq));
                    nq -= 4;
                }
                __half2 h2 = *reinterpret_cast<__half2*>(&pw);
                const float wb = __low2float(h2);
                const float wc = __high2float(h2);
                const float wa = 1.0f - wb - wc;
                float cA = E * wa, cB = E * wb, cC = E * wc;
                if (!valid) { cA = 0.f; cB = 0.f; cC = 0.f; }  // 0*NaN guard
                if (s <= 63) {
                    if (u == 0) { bH_B[(c << 6) | s] = cB;
                                  bH_A[(c << 6) | s] = cA; }
                    if (v == 0) {
                        bV_C[(r << 6) | u] = cC;
                        bV_A[(r << 6) | u] = cA;
                        if (u == 0) ccA[(r << 3) + c] = cA;
                    }
                }
                cA2 = cAp; cAp = cA; cBp = cB; cCp = cC;
                bhA_prev = bhA;
                pw = w2; w2 = w1; w1 = w0;           // rotate for next v
            }
        }
        __syncthreads();
    }

    // ---- reduce temporal term, emit per-batch partial ----
    float a = acc;
    #pragma unroll
    for (int off = 32; off; off >>= 1) a += __shfl_xor(a, off);
    if (u == 0) sred[r] = a;
    __syncthreads();
    if (tid == 0) {
        float ts = 0.f;
        #pragma unroll
        for (int q = 0; q < 8; ++q) ts += sred[q];
        const float temporal = ts * (1.0f / ((float)kN * (float)kN));
        partials[b] = (kAlpha * s_rnn + (1.0f - kAlpha) * temporal)
                    * (1.0f / (float)kB);
    }
}

__global__ void dilate_finalize(const float* __restrict__ partials,
                                float* __restrict__ out) {
    float v = partials[threadIdx.x];   // 64 threads = one wave
    #pragma unroll
    for (int off = 32; off > 0; off >>= 1) v += __shfl_down(v, off);
    if (threadIdx.x == 0) out[0] = v;
}

} // namespace

extern "C" void kernel_launch(void* const* d_in, const int* in_sizes, int n_in,
                              void* d_out, int out_size, void* d_ws, size_t ws_size,
                              hipStream_t stream) {
    (void)in_sizes; (void)n_in; (void)out_size;
    const float* input  = (const float*)d_in[0];
    const float* target = (const float*)d_in[1];
    float* out      = (float*)d_out;
    float* partials = (float*)d_ws;                          // kB floats
    uint32_t* Wbase = (uint32_t*)((char*)d_ws + 1024);       // weight slots

    const size_t per_batch = (size_t)64 * 4096 * sizeof(uint32_t);  // 1 MiB
    const size_t avail = (ws_size > 1024) ? (ws_size - 1024) : 0;
    int cap = (int)(avail / per_batch);
    if (cap > kB) cap = kB;
    if (cap < 1)  cap = 1;

    for (int b0 = 0; b0 < kB; b0 += cap) {
        const int nb = (kB - b0 < cap) ? (kB - b0) : cap;
        hipLaunchKernelGGL(dilate_tiled, dim3(nb), dim3(512), 0, stream,
                           input, target, Wbase, partials, b0);
    }
    hipLaunchKernelGGL(dilate_finalize, dim3(1), dim3(64), 0, stream,
                       partials, out);
}

// Round 5
// 582.170 us; speedup vs baseline: 2.0117x; 2.0117x over previous
//
#include <hip/hip_runtime.h>
#include <cstddef>
#include <cstdint>

namespace {

constexpr int   kN = 512;
constexpr int   kB = 64;
constexpr float kAlpha = 0.8f;
constexpr float kBig  = 1e8f;
constexpr float kKexp = 144.26950408889634f;    // (1/gamma) * log2(e)
constexpr float kGLn2 = 0.006931471805599453f;  // gamma * ln(2)
constexpr float kWexp = 0.07213475204444817f;   // G * log2(e)

typedef __fp16 fp16x2 __attribute__((ext_vector_type(2)));

// One wave (64 lanes) per batch. Lane u owns rows 8u..8u+7 (1-based i = 8u+k+1).
// Step t: lane u processes column j0 = t-u (0-based), cells k=0..7 serially.
// Weights (wb,wc) packed f16x2, stored column-major W[j0*512 + (i-1)].
__global__ __launch_bounds__(64)
void dilate_wave(const float* __restrict__ input,
                 const float* __restrict__ target,
                 uint32_t* __restrict__ Wg,
                 float* __restrict__ partials,
                 int b0)
{
    __shared__ float sx[kN];
    const int u = (int)threadIdx.x;
    const int b = b0 + (int)blockIdx.x;
    uint32_t* __restrict__ Wb = Wg + (size_t)blockIdx.x * (size_t)(kN * kN);

    {
        const float4* in4 = reinterpret_cast<const float4*>(input + (size_t)b * kN);
        float4 a0 = in4[2 * u], a1 = in4[2 * u + 1];
        reinterpret_cast<float4*>(sx)[2 * u]     = a0;
        reinterpret_cast<float4*>(sx)[2 * u + 1] = a1;
    }
    float tk[8], wk[8];
    {
        const float4* tg4 = reinterpret_cast<const float4*>(target + (size_t)b * kN);
        float4 a0 = tg4[2 * u], a1 = tg4[2 * u + 1];
        tk[0]=a0.x; tk[1]=a0.y; tk[2]=a0.z; tk[3]=a0.w;
        tk[4]=a1.x; tk[5]=a1.y; tk[6]=a1.z; tk[7]=a1.w;
    }
    float esum = 0.0f;
    float ewv[8];
    #pragma unroll
    for (int k = 0; k < 8; ++k) {
        ewv[k] = exp2f(kWexp * (float)(8 * u + k));
        esum += ewv[k];
    }
    #pragma unroll
    for (int off = 32; off; off >>= 1) esum += __shfl_xor(esum, off);
    const float nrm = 512.0f / esum;
    #pragma unroll
    for (int k = 0; k < 8; ++k) wk[k] = ewv[k] * nrm;
    __syncthreads();

    // ================= forward soft-DTW =================
    float Cst[8];
    #pragma unroll
    for (int k = 0; k < 8; ++k) Cst[k] = kBig;
    float bval = kBig, aval = kBig;   // lane u-1 slot7 values from t-1 / t-2
    float xj = sx[0];
    for (int t = 0; t < 575; ++t) {
        const int jc = t - u;
        const bool valid = (jc >= 0) && (jc <= 511);
        int jn = jc + 1; jn = jn < 0 ? 0 : (jn > 511 ? 511 : jn);
        const float xnx = sx[jn];                 // prefetch next column's x
        float Acur = aval, Bcur = bval;
        if (u == 0) { Bcur = kBig; Acur = (t == 0) ? 0.0f : kBig; }
        uint32_t pk[8];
        #pragma unroll
        for (int k = 0; k < 8; ++k) {
            const float Ck = Cst[k];              // R[i_k][j-1]
            const float m  = fminf(Bcur, fminf(Acur, Ck));
            const float eA = exp2f((m - Acur) * kKexp);
            const float eB = exp2f((m - Bcur) * kKexp);
            const float eC = exp2f((m - Ck)   * kKexp);
            const float ss = eA + eB + eC;
            const float dx = tk[k] - xj;
            float cur = fmaf(wk[k] * dx, dx, m - kGLn2 * __log2f(ss));
            const float ri = __builtin_amdgcn_rcpf(ss);
            fp16x2 hp = __builtin_amdgcn_cvt_pkrtz(eB * ri, eC * ri);
            pk[k] = __builtin_bit_cast(uint32_t, hp);
            cur = valid ? cur : kBig;
            Cst[k] = cur;
            Acur = Ck;                            // A for slot k+1
            Bcur = cur;                           // B for slot k+1
        }
        if (valid) {
            uint32_t* p = Wb + (size_t)jc * kN + 8 * u;
            uint4 s0; s0.x = pk[0]; s0.y = pk[1]; s0.z = pk[2]; s0.w = pk[3];
            uint4 s1; s1.x = pk[4]; s1.y = pk[5]; s1.z = pk[6]; s1.w = pk[7];
            *reinterpret_cast<uint4*>(p)     = s0;
            *reinterpret_cast<uint4*>(p + 4) = s1;
        }
        aval = bval;
        bval = __shfl_up(Cst[7], 1);
        xj = xnx;
    }
    const float rnn = __shfl(Cst[7], 63);         // R[512][512]

    __threadfence();                              // stores visible to own reads

    // ================= backward adjoint (reversed coords) =================
    // primed i' = 512-i+1... identical stencil; lane u owns i' = 8u+1..8u+8.
    // E'[cell] = cA_old[k-1] + cB_new[k-1] + cC_old[k]; c* = E*w* of that cell.
    float cA[8], cC[8];
    #pragma unroll
    for (int k = 0; k < 8; ++k) { cA[k] = 0.0f; cC[k] = 0.0f; }
    float shB = 0.0f, shA = 0.0f, shAp = 0.0f, cB7 = 0.0f;
    float acc = 0.0f;
    float dbase = (float)(-9 * u);                // i - j = t - 9u - k
    const int ubase = 504 - 8 * u;                // chunk rows i-1 = 504-8u..511-8u

    auto wld = [&](int t, uint4& lo, uint4& hi) {
        int row = 511 - t + u;
        row = row < 0 ? 0 : (row > 511 ? 511 : row);
        const uint4* p = reinterpret_cast<const uint4*>(
            Wb + (size_t)row * kN + ubase);
        lo = p[0]; hi = p[1];
    };
    uint4 l0, h0, l1, h1, l2, h2, l3, h3;
    wld(0, l0, h0); wld(1, l1, h1); wld(2, l2, h2); wld(3, l3, h3);

#define BSTEP(T, LO, HI, SEED)                                              \
    {                                                                       \
        const int t_ = (T);                                                 \
        const int jc_ = t_ - u;                                             \
        const bool val_ = (jc_ >= 0) && (jc_ <= 511);                       \
        uint32_t q[8];                                                      \
        q[7] = LO.x; q[6] = LO.y; q[5] = LO.z; q[4] = LO.w;                 \
        q[3] = HI.x; q[2] = HI.y; q[1] = HI.z; q[0] = HI.w;                 \
        if (!val_) {                                                        \
            _Pragma("unroll") for (int k = 0; k < 8; ++k) q[k] = 0u;        \
        }                                                                   \
        float At = shA, Bt = shB;                                           \
        if (u == 0) { At = 0.0f; Bt = 0.0f; }                               \
        _Pragma("unroll")                                                   \
        for (int k = 0; k < 8; ++k) {                                       \
            float E = At + Bt + cC[k];                                      \
            if ((SEED) && k == 0 && u == 0) E = 1.0f;                       \
            E = val_ ? E : 0.0f;                                            \
            const float dij = dbase - (float)k;                             \
            acc = fmaf(E * dij, dij, acc);                                  \
            fp16x2 h_ = __builtin_bit_cast(fp16x2, q[k]);                   \
            const float wb_ = (float)h_[0], wc_ = (float)h_[1];             \
            const float wa_ = 1.0f - wb_ - wc_;                             \
            const float nA = E * wa_, nB = E * wb_, nC = E * wc_;           \
            At = cA[k];                                                     \
            Bt = nB;                                                        \
            cA[k] = nA; cC[k] = nC;                                         \
            if (k == 7) cB7 = nB;                                           \
        }                                                                   \
        const float tB_ = __shfl_up(cB7, 1);                                \
        const float tA_ = __shfl_up(cA[7], 1);                              \
        shB = tB_; shA = shAp; shAp = tA_;                                  \
        dbase += 1.0f;                                                      \
        wld(t_ + 4, LO, HI);                                                \
    }

    for (int tg = 0; tg < 576; tg += 4) {
        const bool sd = (tg == 0);
        BSTEP(tg + 0, l0, h0, sd)
        BSTEP(tg + 1, l1, h1, false)
        BSTEP(tg + 2, l2, h2, false)
        BSTEP(tg + 3, l3, h3, false)
    }
#undef BSTEP

    #pragma unroll
    for (int off = 32; off; off >>= 1) acc += __shfl_xor(acc, off);
    if (u == 0) {
        const float temporal = acc * (1.0f / (512.0f * 512.0f));
        partials[b] = (kAlpha * rnn + (1.0f - kAlpha) * temporal)
                    * (1.0f / (float)kB);
    }
}

__global__ void dilate_finalize(const float* __restrict__ partials,
                                float* __restrict__ out) {
    float v = partials[threadIdx.x];   // 64 threads = one wave
    #pragma unroll
    for (int off = 32; off > 0; off >>= 1) v += __shfl_down(v, off);
    if (threadIdx.x == 0) out[0] = v;
}

} // namespace

extern "C" void kernel_launch(void* const* d_in, const int* in_sizes, int n_in,
                              void* d_out, int out_size, void* d_ws, size_t ws_size,
                              hipStream_t stream) {
    (void)in_sizes; (void)n_in; (void)out_size;
    const float* input  = (const float*)d_in[0];
    const float* target = (const float*)d_in[1];
    float* out      = (float*)d_out;
    float* partials = (float*)d_ws;                          // kB floats
    uint32_t* Wbase = (uint32_t*)((char*)d_ws + 1024);       // weight slots

    const size_t per_batch = (size_t)kN * kN * sizeof(uint32_t);  // 1 MiB
    const size_t avail = (ws_size > 1024) ? (ws_size - 1024) : 0;
    int cap = (int)(avail / per_batch);
    if (cap > kB) cap = kB;
    if (cap < 1)  cap = 1;

    for (int b0 = 0; b0 < kB; b0 += cap) {
        const int nb = (kB - b0 < cap) ? (kB - b0) : cap;
        hipLaunchKernelGGL(dilate_wave, dim3(nb), dim3(64), 0, stream,
                           input, target, Wbase, partials, b0);
    }
    hipLaunchKernelGGL(dilate_finalize, dim3(1), dim3(64), 0, stream,
                       partials, out);
}

// Round 6
// 519.426 us; speedup vs baseline: 2.2547x; 1.1208x over previous
//
#include <hip/hip_runtime.h>
#include <cstddef>
#include <cstdint>

namespace {

constexpr int   kN = 512;
constexpr int   kB = 64;
constexpr float kAlpha = 0.8f;
constexpr float kBig  = 1e8f;
constexpr float kKexp = 144.26950408889634f;    // (1/gamma) * log2(e)
constexpr float kGLn2 = 0.006931471805599453f;  // gamma * ln(2)
constexpr float kWexp = 0.07213475204444817f;   // G * log2(e)

typedef __fp16 fp16x2 __attribute__((ext_vector_type(2)));

// One wave (64 lanes) per batch. Lane u owns rows 8u..8u+7 (1-based i = 8u+k+1).
// Step t: lane u processes column j0 = t-u (0-based), cells k=0..7 serially.
// Weights (wb,wc) packed f16x2, stored column-major W[j0*512 + (i-1)].
__global__ __launch_bounds__(64)
void dilate_wave(const float* __restrict__ input,
                 const float* __restrict__ target,
                 uint32_t* __restrict__ Wg,
                 float* __restrict__ partials,
                 int b0)
{
    __shared__ float sx[kN];
    const int u = (int)threadIdx.x;
    const int b = b0 + (int)blockIdx.x;
    uint32_t* __restrict__ Wb = Wg + (size_t)blockIdx.x * (size_t)(kN * kN);

    {
        const float4* in4 = reinterpret_cast<const float4*>(input + (size_t)b * kN);
        float4 a0 = in4[2 * u], a1 = in4[2 * u + 1];
        reinterpret_cast<float4*>(sx)[2 * u]     = a0;
        reinterpret_cast<float4*>(sx)[2 * u + 1] = a1;
    }
    float tk[8], wk[8];
    {
        const float4* tg4 = reinterpret_cast<const float4*>(target + (size_t)b * kN);
        float4 a0 = tg4[2 * u], a1 = tg4[2 * u + 1];
        tk[0]=a0.x; tk[1]=a0.y; tk[2]=a0.z; tk[3]=a0.w;
        tk[4]=a1.x; tk[5]=a1.y; tk[6]=a1.z; tk[7]=a1.w;
    }
    float esum = 0.0f;
    float ewv[8];
    #pragma unroll
    for (int k = 0; k < 8; ++k) {
        ewv[k] = exp2f(kWexp * (float)(8 * u + k));
        esum += ewv[k];
    }
    #pragma unroll
    for (int off = 32; off; off >>= 1) esum += __shfl_xor(esum, off);
    const float nrm = 512.0f / esum;
    #pragma unroll
    for (int k = 0; k < 8; ++k) wk[k] = ewv[k] * nrm;
    __syncthreads();

    // ================= forward soft-DTW =================
    float Cst[8];
    #pragma unroll
    for (int k = 0; k < 8; ++k) Cst[k] = kBig;
    float bval = kBig, aval = kBig;   // lane u-1 slot7 values from t-1 / t-2
    float xj = sx[0];

#define FSTEP(T, CHECKED)                                                   \
    {                                                                       \
        const int t_ = (T);                                                 \
        const int jc_ = t_ - u;                                             \
        bool valid_ = true;                                                 \
        int jn_ = jc_ + 1;                                                  \
        if (CHECKED) {                                                      \
            valid_ = (jc_ >= 0) && (jc_ <= 511);                            \
            jn_ = jn_ < 0 ? 0 : (jn_ > 511 ? 511 : jn_);                    \
        }                                                                   \
        const float xnx = sx[jn_];                                          \
        float Acur = aval, Bcur = bval;                                     \
        if (u == 0) { Bcur = kBig; Acur = (t_ == 0) ? 0.0f : kBig; }        \
        uint32_t pk[8];                                                     \
        _Pragma("unroll")                                                   \
        for (int k = 0; k < 8; ++k) {                                       \
            const float Ck = Cst[k];                                        \
            const float m  = fminf(Bcur, fminf(Acur, Ck));                  \
            const float eA = exp2f((m - Acur) * kKexp);                     \
            const float eB = exp2f((m - Bcur) * kKexp);                     \
            const float eC = exp2f((m - Ck)   * kKexp);                     \
            const float ss = eA + eB + eC;                                  \
            const float dx = tk[k] - xj;                                    \
            float cur = fmaf(wk[k] * dx, dx, m - kGLn2 * __log2f(ss));      \
            const float ri = __builtin_amdgcn_rcpf(ss);                     \
            fp16x2 hp = __builtin_amdgcn_cvt_pkrtz(eB * ri, eC * ri);       \
            pk[k] = __builtin_bit_cast(uint32_t, hp);                       \
            if (CHECKED) cur = valid_ ? cur : kBig;                         \
            Cst[k] = cur;                                                   \
            Acur = Ck;                                                      \
            Bcur = cur;                                                     \
        }                                                                   \
        if (valid_) {                                                       \
            uint32_t* p_ = Wb + (size_t)jc_ * kN + 8 * u;                   \
            uint4 s0; s0.x = pk[0]; s0.y = pk[1]; s0.z = pk[2]; s0.w = pk[3];\
            uint4 s1; s1.x = pk[4]; s1.y = pk[5]; s1.z = pk[6]; s1.w = pk[7];\
            *reinterpret_cast<uint4*>(p_)     = s0;                         \
            *reinterpret_cast<uint4*>(p_ + 4) = s1;                         \
        }                                                                   \
        aval = bval;                                                        \
        bval = __shfl_up(Cst[7], 1);                                        \
        xj = xnx;                                                           \
    }

    for (int t = 0; t < 63; ++t)   FSTEP(t, true)
    for (int t = 63; t < 511; ++t) FSTEP(t, false)
    for (int t = 511; t < 575; ++t) FSTEP(t, true)
#undef FSTEP

    const float rnn = __shfl(Cst[7], 63);         // R[512][512]

    __threadfence();                              // stores visible to own reads

    // ================= backward adjoint (reversed coords) =================
    // primed i' = 512-i+1; lane u owns i' = 8u+1..8u+8.
    // E'[cell] = cA_old[k-1] + cB_new[k-1] + cC_old[k]; c* = E*w* of that cell.
    float cA[8], cC[8];
    #pragma unroll
    for (int k = 0; k < 8; ++k) { cA[k] = 0.0f; cC[k] = 0.0f; }
    float shB = 0.0f, shA = 0.0f, shAp = 0.0f, cB7 = 0.0f;
    float acc = 0.0f;
    float dbase = (float)(-9 * u);                // i - j = t - 9u - k
    const int ubase = 504 - 8 * u;                // chunk rows i-1 = 504-8u..511-8u

    auto wld = [&](int t, uint4& lo, uint4& hi) {
        int row = 511 - t + u;
        row = row < 0 ? 0 : (row > 511 ? 511 : row);
        const uint4* p = reinterpret_cast<const uint4*>(
            Wb + (size_t)row * kN + ubase);
        lo = p[0]; hi = p[1];
    };
    uint4 L0,H0,L1,H1,L2,H2,L3,H3,L4,H4,L5,H5,L6,H6,L7,H7;
    wld(0,L0,H0); wld(1,L1,H1); wld(2,L2,H2); wld(3,L3,H3);
    wld(4,L4,H4); wld(5,L5,H5); wld(6,L6,H6); wld(7,L7,H7);

#define BSTEP(T, LO, HI, CHECKED, SEED)                                     \
    {                                                                       \
        const int t_ = (T);                                                 \
        const int jc_ = t_ - u;                                             \
        bool val_ = true;                                                   \
        if (CHECKED) val_ = (jc_ >= 0) && (jc_ <= 511);                     \
        uint32_t q[8];                                                      \
        q[7] = LO.x; q[6] = LO.y; q[5] = LO.z; q[4] = LO.w;                 \
        q[3] = HI.x; q[2] = HI.y; q[1] = HI.z; q[0] = HI.w;                 \
        if (CHECKED && !val_) {                                             \
            _Pragma("unroll") for (int k = 0; k < 8; ++k) q[k] = 0u;        \
        }                                                                   \
        float At = shA, Bt = shB;                                           \
        if (u == 0) { At = 0.0f; Bt = 0.0f; }                               \
        _Pragma("unroll")                                                   \
        for (int k = 0; k < 8; ++k) {                                       \
            float E = At + Bt + cC[k];                                      \
            if ((SEED) && k == 0 && u == 0) E = 1.0f;                       \
            if (CHECKED) E = val_ ? E : 0.0f;                               \
            const float dij = dbase - (float)k;                             \
            acc = fmaf(E * dij, dij, acc);                                  \
            fp16x2 h_ = __builtin_bit_cast(fp16x2, q[k]);                   \
            const float wb_ = (float)h_[0], wc_ = (float)h_[1];             \
            const float wa_ = 1.0f - wb_ - wc_;                             \
            const float nA = E * wa_, nB = E * wb_, nC = E * wc_;           \
            At = cA[k];                                                     \
            Bt = nB;                                                        \
            cA[k] = nA; cC[k] = nC;                                         \
            if (k == 7) cB7 = nB;                                           \
        }                                                                   \
        const float tB_ = __shfl_up(cB7, 1);                                \
        const float tA_ = __shfl_up(cA[7], 1);                              \
        shB = tB_; shA = shAp; shAp = tA_;                                  \
        dbase += 1.0f;                                                      \
        wld(t_ + 8, LO, HI);                                                \
    }

    // prologue t in [0,64)
    BSTEP(0, L0, H0, true, true)
    BSTEP(1, L1, H1, true, false)
    BSTEP(2, L2, H2, true, false)
    BSTEP(3, L3, H3, true, false)
    BSTEP(4, L4, H4, true, false)
    BSTEP(5, L5, H5, true, false)
    BSTEP(6, L6, H6, true, false)
    BSTEP(7, L7, H7, true, false)
    for (int tg = 8; tg < 64; tg += 8) {
        BSTEP(tg + 0, L0, H0, true, false)
        BSTEP(tg + 1, L1, H1, true, false)
        BSTEP(tg + 2, L2, H2, true, false)
        BSTEP(tg + 3, L3, H3, true, false)
        BSTEP(tg + 4, L4, H4, true, false)
        BSTEP(tg + 5, L5, H5, true, false)
        BSTEP(tg + 6, L6, H6, true, false)
        BSTEP(tg + 7, L7, H7, true, false)
    }
    // steady t in [64,512)
    for (int tg = 64; tg < 512; tg += 8) {
        BSTEP(tg + 0, L0, H0, false, false)
        BSTEP(tg + 1, L1, H1, false, false)
        BSTEP(tg + 2, L2, H2, false, false)
        BSTEP(tg + 3, L3, H3, false, false)
        BSTEP(tg + 4, L4, H4, false, false)
        BSTEP(tg + 5, L5, H5, false, false)
        BSTEP(tg + 6, L6, H6, false, false)
        BSTEP(tg + 7, L7, H7, false, false)
    }
    // epilogue t in [512,576)
    for (int tg = 512; tg < 576; tg += 8) {
        BSTEP(tg + 0, L0, H0, true, false)
        BSTEP(tg + 1, L1, H1, true, false)
        BSTEP(tg + 2, L2, H2, true, false)
        BSTEP(tg + 3, L3, H3, true, false)
        BSTEP(tg + 4, L4, H4, true, false)
        BSTEP(tg + 5, L5, H5, true, false)
        BSTEP(tg + 6, L6, H6, true, false)
        BSTEP(tg + 7, L7, H7, true, false)
    }
#undef BSTEP

    #pragma unroll
    for (int off = 32; off; off >>= 1) acc += __shfl_xor(acc, off);
    if (u == 0) {
        const float temporal = acc * (1.0f / (512.0f * 512.0f));
        partials[b] = (kAlpha * rnn + (1.0f - kAlpha) * temporal)
                    * (1.0f / (float)kB);
    }
}

__global__ void dilate_finalize(const float* __restrict__ partials,
                                float* __restrict__ out) {
    float v = partials[threadIdx.x];   // 64 threads = one wave
    #pragma unroll
    for (int off = 32; off > 0; off >>= 1) v += __shfl_down(v, off);
    if (threadIdx.x == 0) out[0] = v;
}

} // namespace

extern "C" void kernel_launch(void* const* d_in, const int* in_sizes, int n_in,
                              void* d_out, int out_size, void* d_ws, size_t ws_size,
                              hipStream_t stream) {
    (void)in_sizes; (void)n_in; (void)out_size;
    const float* input  = (const float*)d_in[0];
    const float* target = (const float*)d_in[1];
    float* out      = (float*)d_out;
    float* partials = (float*)d_ws;                          // kB floats
    uint32_t* Wbase = (uint32_t*)((char*)d_ws + 1024);       // weight slots

    const size_t per_batch = (size_t)kN * kN * sizeof(uint32_t);  // 1 MiB
    const size_t avail = (ws_size > 1024) ? (ws_size - 1024) : 0;
    int cap = (int)(avail / per_batch);
    if (cap > kB) cap = kB;
    if (cap < 1)  cap = 1;

    for (int b0 = 0; b0 < kB; b0 += cap) {
        const int nb = (kB - b0 < cap) ? (kB - b0) : cap;
        hipLaunchKernelGGL(dilate_wave, dim3(nb), dim3(64), 0, stream,
                           input, target, Wbase, partials, b0);
    }
    hipLaunchKernelGGL(dilate_finalize, dim3(1), dim3(64), 0, stream,
                       partials, out);
}

// Round 7
// 495.205 us; speedup vs baseline: 2.3650x; 1.0489x over previous
//
#include <hip/hip_runtime.h>
#include <cstddef>
#include <cstdint>

namespace {

constexpr int   kN = 512;
constexpr int   kB = 64;
constexpr float kAlpha = 0.8f;
constexpr float kBig  = 1e8f;
constexpr float kKexp = 144.26950408889634f;    // (1/gamma) * log2(e)
constexpr float kGLn2 = 0.006931471805599453f;  // gamma * ln(2)
constexpr float kWexp = 0.07213475204444817f;   // G * log2(e)

constexpr int W     = 4;     // waves per block (one per SIMD)
constexpr int DELTA = 16;    // global steps between block barriers
constexpr int LAM   = 80;    // per-wave lag = 64 + DELTA
constexpr int SMAX  = 574;   // last local step per wave (inclusive)
constexpr int GTOT  = 816;   // 51 supersteps cover g = 0..815 (need 814)

typedef __fp16 fp16x2 __attribute__((ext_vector_type(2)));

// 4 staggered waves per batch. Wave w owns rows [128w,128w+128); lane u owns
// rows r0=2*tid, r1=2*tid+1 (tid = 64w+u). At local step s lane u handles
// column c=s-u, cells k=0,1 serially. Wave w runs at global step g=s+80w.
// Row boundaries between waves pass through LDS rings; barrier every 16 steps
// guarantees producer data crossed >=1 barrier before consumption (lag 17).
__global__ __launch_bounds__(256)
void dilate_wave4(const float* __restrict__ input,
                  const float* __restrict__ target,
                  uint32_t* __restrict__ Wg,
                  float* __restrict__ partials,
                  int b0)
{
    __shared__ float sx[kN];
    __shared__ float ringB[W][128];   // fwd: R row-boundary; bwd: cB boundary
    __shared__ float ringA[W][128];   // bwd: cA boundary
    __shared__ float sred[W];
    __shared__ float s_rnn;

    const int tid = (int)threadIdx.x;
    const int w = tid >> 6, u = tid & 63;
    const int wprev = (w > 0) ? (w - 1) : 0;
    const bool topw = (w == 0);
    const int b = b0 + (int)blockIdx.x;
    const int sOff = w * LAM;
    uint32_t* __restrict__ Wb = Wg + (size_t)blockIdx.x * (size_t)(kN * kN);

    float2 xv = reinterpret_cast<const float2*>(input + (size_t)b * kN)[tid];
    sx[2 * tid] = xv.x; sx[2 * tid + 1] = xv.y;
    float2 tv = reinterpret_cast<const float2*>(target + (size_t)b * kN)[tid];
    const float tk0 = tv.x, tk1 = tv.y;

    // normalized exponential time weights (rows 2tid, 2tid+1)
    float e0 = exp2f(kWexp * (float)(2 * tid));
    float e1 = exp2f(kWexp * (float)(2 * tid + 1));
    float es = e0 + e1;
    #pragma unroll
    for (int off = 32; off; off >>= 1) es += __shfl_xor(es, off);
    if (u == 0) sred[w] = es;
    __syncthreads();
    const float tot = sred[0] + sred[1] + sred[2] + sred[3];
    const float nrm = 512.0f / tot;
    const float wk0 = e0 * nrm, wk1 = e1 * nrm;

    // ================= forward soft-DTW =================
    float C0 = kBig, C1 = kBig;
    float aval = kBig, bval = kBig, prevRB = kBig;
    float xj = sx[0];

    for (int m = 0; m < GTOT / DELTA; ++m) {
        for (int dg = 0; dg < DELTA; ++dg) {
            const int s = m * DELTA + dg - sOff;
            if (s >= 0 && s <= SMAX) {
                const int c = s - u;
                const bool valid = (c >= 0) & (c <= 511);
                const float rB = ringB[wprev][s & 127];
                float Acur, Bcur;
                if (u == 0) {
                    if (topw) { Bcur = kBig; Acur = (s == 0) ? 0.0f : kBig; }
                    else      { Bcur = rB;   Acur = prevRB; }
                } else { Acur = aval; Bcur = bval; }
                prevRB = rB;
                // cell 0 (row 2tid): A,B from row above; C own
                const float m0 = fminf(Bcur, fminf(Acur, C0));
                const float eA0 = exp2f((m0 - Acur) * kKexp);
                const float eB0 = exp2f((m0 - Bcur) * kKexp);
                const float eC0 = exp2f((m0 - C0)   * kKexp);
                const float ss0 = eA0 + eB0 + eC0;
                const float dx0 = tk0 - xj;
                float cur0 = fmaf(wk0 * dx0, dx0, m0 - kGLn2 * __log2f(ss0));
                const float ri0 = __builtin_amdgcn_rcpf(ss0);
                fp16x2 hp0 = __builtin_amdgcn_cvt_pkrtz(eB0 * ri0, eC0 * ri0);
                cur0 = valid ? cur0 : kBig;
                // cell 1 (row 2tid+1): A = old C0, B = cur0, C = C1
                const float m1 = fminf(cur0, fminf(C0, C1));
                const float eA1 = exp2f((m1 - C0)   * kKexp);
                const float eB1 = exp2f((m1 - cur0) * kKexp);
                const float eC1 = exp2f((m1 - C1)   * kKexp);
                const float ss1 = eA1 + eB1 + eC1;
                const float dx1 = tk1 - xj;
                float cur1 = fmaf(wk1 * dx1, dx1, m1 - kGLn2 * __log2f(ss1));
                const float ri1 = __builtin_amdgcn_rcpf(ss1);
                fp16x2 hp1 = __builtin_amdgcn_cvt_pkrtz(eB1 * ri1, eC1 * ri1);
                cur1 = valid ? cur1 : kBig;
                C0 = cur0; C1 = cur1;
                if (valid) {
                    uint2 st;
                    st.x = __builtin_bit_cast(uint32_t, hp0);
                    st.y = __builtin_bit_cast(uint32_t, hp1);
                    *reinterpret_cast<uint2*>(Wb + (size_t)c * kN + 2 * tid) = st;
                }
                if (u == 63 && valid) ringB[w][c & 127] = cur1;
                aval = bval;
                bval = __shfl_up(C1, 1);
                int cn = c + 1; cn = cn < 0 ? 0 : (cn > 511 ? 511 : cn);
                xj = sx[cn];
            }
        }
        __syncthreads();
    }
    if (tid == 255) s_rnn = C1;    // R[512][512]
    __threadfence();
    __syncthreads();

    // ================= backward adjoint (primed coords) =================
    // primed row p = 511 - original row; wave w owns primed band [128w,+128).
    float cA0 = 0.0f, cC0 = 0.0f, cC1 = 0.0f;
    float shB = 0.0f, shA = 0.0f, shAp = 0.0f, savedBA = 0.0f;
    float acc = 0.0f;
    const int rbase = 510 - 2 * tid;   // original row pair [rbase, rbase+1]

    auto addr = [&](int s) -> const uint2* {
        int jc = 511 - (s - u);        // original 0-based column
        jc = jc < 0 ? 0 : (jc > 511 ? 511 : jc);
        return reinterpret_cast<const uint2*>(Wb + (size_t)jc * kN + rbase);
    };
    uint2 P0 = *addr(0), P1 = *addr(1), P2 = *addr(2), P3 = *addr(3);
    uint2 P4 = *addr(4), P5 = *addr(5), P6 = *addr(6), P7 = *addr(7);

#define BS(DG, P)                                                           \
    {                                                                       \
        const int s = m * DELTA + (DG) - sOff;                              \
        if (s >= 0 && s <= SMAX) {                                          \
            const int c = s - u;                                            \
            const bool valid = (c >= 0) & (c <= 511);                       \
            const float rBB = ringB[wprev][s & 127];                        \
            const float rBA = ringA[wprev][s & 127];                        \
            float At0, Bt0;                                                 \
            if (u == 0) {                                                   \
                if (topw) { At0 = 0.0f; Bt0 = 0.0f; }                       \
                else      { At0 = savedBA; Bt0 = rBB; }                     \
            } else { At0 = shA; Bt0 = shB; }                                \
            savedBA = rBA;                                                  \
            float E0 = At0 + Bt0 + cC0;                                     \
            if (topw && u == 0 && s == 0) E0 = 1.0f;   /* seed E[N,N] */    \
            E0 = valid ? E0 : 0.0f;                                         \
            const float d0 = (float)(c - 2 * tid);                          \
            acc = fmaf(E0 * d0, d0, acc);                                   \
            fp16x2 h0 = __builtin_bit_cast(fp16x2, P.y);                    \
            const float wb0 = (float)h0[0], wc0 = (float)h0[1];             \
            const float nA0 = E0 * (1.0f - wb0 - wc0);                      \
            const float nB0 = E0 * wb0, nC0 = E0 * wc0;                     \
            float E1 = cA0 + nB0 + cC1;                                     \
            E1 = valid ? E1 : 0.0f;                                         \
            const float d1 = d0 - 1.0f;                                     \
            acc = fmaf(E1 * d1, d1, acc);                                   \
            fp16x2 h1 = __builtin_bit_cast(fp16x2, P.x);                    \
            const float wb1 = (float)h1[0], wc1 = (float)h1[1];             \
            const float nA1 = E1 * (1.0f - wb1 - wc1);                      \
            const float nB1 = E1 * wb1, nC1 = E1 * wc1;                     \
            cA0 = nA0; cC0 = nC0; cC1 = nC1;                                \
            if (u == 63 && valid) {                                         \
                ringB[w][c & 127] = nB1;                                    \
                ringA[w][c & 127] = nA1;                                    \
            }                                                               \
            const float tB = __shfl_up(nB1, 1);                             \
            const float tA = __shfl_up(nA1, 1);                             \
            shB = tB; shA = shAp; shAp = tA;                                \
            P = *addr(s + 8);                                               \
        }                                                                   \
    }

    for (int m = 0; m < GTOT / DELTA; ++m) {
        BS(0,  P0) BS(1,  P1) BS(2,  P2) BS(3,  P3)
        BS(4,  P4) BS(5,  P5) BS(6,  P6) BS(7,  P7)
        BS(8,  P0) BS(9,  P1) BS(10, P2) BS(11, P3)
        BS(12, P4) BS(13, P5) BS(14, P6) BS(15, P7)
        __syncthreads();
    }
#undef BS

    // ---- reduce temporal term, emit per-batch partial ----
    #pragma unroll
    for (int off = 32; off; off >>= 1) acc += __shfl_xor(acc, off);
    if (u == 0) sred[w] = acc;
    __syncthreads();
    if (tid == 0) {
        const float ts = sred[0] + sred[1] + sred[2] + sred[3];
        const float temporal = ts * (1.0f / (512.0f * 512.0f));
        partials[b] = (kAlpha * s_rnn + (1.0f - kAlpha) * temporal)
                    * (1.0f / (float)kB);
    }
}

__global__ void dilate_finalize(const float* __restrict__ partials,
                                float* __restrict__ out) {
    float v = partials[threadIdx.x];   // 64 threads = one wave
    #pragma unroll
    for (int off = 32; off > 0; off >>= 1) v += __shfl_down(v, off);
    if (threadIdx.x == 0) out[0] = v;
}

} // namespace

extern "C" void kernel_launch(void* const* d_in, const int* in_sizes, int n_in,
                              void* d_out, int out_size, void* d_ws, size_t ws_size,
                              hipStream_t stream) {
    (void)in_sizes; (void)n_in; (void)out_size;
    const float* input  = (const float*)d_in[0];
    const float* target = (const float*)d_in[1];
    float* out      = (float*)d_out;
    float* partials = (float*)d_ws;                          // kB floats
    uint32_t* Wbase = (uint32_t*)((char*)d_ws + 1024);       // weight slots

    const size_t per_batch = (size_t)kN * kN * sizeof(uint32_t);  // 1 MiB
    const size_t avail = (ws_size > 1024) ? (ws_size - 1024) : 0;
    int cap = (int)(avail / per_batch);
    if (cap > kB) cap = kB;
    if (cap < 1)  cap = 1;

    for (int b0 = 0; b0 < kB; b0 += cap) {
        const int nb = (kB - b0 < cap) ? (kB - b0) : cap;
        hipLaunchKernelGGL(dilate_wave4, dim3(nb), dim3(256), 0, stream,
                           input, target, Wbase, partials, b0);
    }
    hipLaunchKernelGGL(dilate_finalize, dim3(1), dim3(64), 0, stream,
                       partials, out);
}